// Round 1
// baseline (349.344 us; speedup 1.0000x reference)
//
#include <hip/hip_runtime.h>

#define HID    128
#define SEQ    512
#define BATCH  256
#define DIM    300
#define VOCAB  50000
#define VT     16      // vocab rows per proj block
#define ETP    20      // padded (and 16B-aligned) stride of transposed emb tile

// ---------------------------------------------------------------------------
// Kernel A: P[v][h] = dot(emb[v,:], W_ih[h,:]) + b_ih[h] + b_hh[h]
// Tall-skinny f32 GEMM, M=50000, N=128, K=300. One block = 16 vocab rows.
// emb tile staged TRANSPOSED in LDS so each thread reads 16 v-values for a
// given k as 4x ds_read_b128 (broadcast across the wave -> conflict-free).
// ---------------------------------------------------------------------------
__global__ __launch_bounds__(128)
void proj_kernel(const float* __restrict__ emb,
                 const float* __restrict__ Wih,
                 const float* __restrict__ bih,
                 const float* __restrict__ bhh,
                 float* __restrict__ P)
{
    __shared__ float et[DIM * ETP];   // et[k*ETP + r], r = local vocab row
    const int tid = threadIdx.x;
    const int v0  = blockIdx.x * VT;

    // stage 16 emb rows, transposed (global reads coalesced along k)
    #pragma unroll
    for (int r = 0; r < VT; ++r) {
        const float* src = emb + (size_t)(v0 + r) * DIM;
        for (int k = tid; k < DIM; k += 128)
            et[k * ETP + r] = src[k];
    }
    __syncthreads();

    const int h = tid;               // 128 threads = 128 hidden units
    float acc[VT];
    #pragma unroll
    for (int r = 0; r < VT; ++r) acc[r] = 0.f;

    const float* wrow = Wih + (size_t)h * DIM;
    for (int k4 = 0; k4 < DIM / 4; ++k4) {
        const float4 w = *(const float4*)(wrow + k4 * 4);
        #pragma unroll
        for (int jj = 0; jj < 4; ++jj) {
            const float wv = (jj == 0) ? w.x : (jj == 1) ? w.y : (jj == 2) ? w.z : w.w;
            const float* eb = et + (k4 * 4 + jj) * ETP;
            const float4 e0 = *(const float4*)(eb + 0);
            const float4 e1 = *(const float4*)(eb + 4);
            const float4 e2 = *(const float4*)(eb + 8);
            const float4 e3 = *(const float4*)(eb + 12);
            acc[0]  = fmaf(wv, e0.x, acc[0]);   acc[1]  = fmaf(wv, e0.y, acc[1]);
            acc[2]  = fmaf(wv, e0.z, acc[2]);   acc[3]  = fmaf(wv, e0.w, acc[3]);
            acc[4]  = fmaf(wv, e1.x, acc[4]);   acc[5]  = fmaf(wv, e1.y, acc[5]);
            acc[6]  = fmaf(wv, e1.z, acc[6]);   acc[7]  = fmaf(wv, e1.w, acc[7]);
            acc[8]  = fmaf(wv, e2.x, acc[8]);   acc[9]  = fmaf(wv, e2.y, acc[9]);
            acc[10] = fmaf(wv, e2.z, acc[10]);  acc[11] = fmaf(wv, e2.w, acc[11]);
            acc[12] = fmaf(wv, e3.x, acc[12]);  acc[13] = fmaf(wv, e3.y, acc[13]);
            acc[14] = fmaf(wv, e3.z, acc[14]);  acc[15] = fmaf(wv, e3.w, acc[15]);
        }
    }

    const float bb = bih[h] + bhh[h];   // fold BOTH biases into the table
    #pragma unroll
    for (int r = 0; r < VT; ++r)
        P[(size_t)(v0 + r) * HID + h] = acc[r] + bb;   // coalesced across h
}

// ---------------------------------------------------------------------------
// Kernel B: per-batch sequential RNN. grid=256 (1 block/CU), block=512.
// Thread t: output row i = t>>2, k-quarter kq = t&3 (32 W_hh values in VGPRs).
// h double-buffered in LDS; ONE barrier per step. Read order rotated per kq
// ((j+2kq)&7, folded into the W register load so reg indices stay static)
// so the 4 distinct ds_read_b128 addresses per instruction hit distinct
// bank quads -> conflict-free broadcast reads.
// Running max/sum pooling in registers; fused FC epilogue.
// ---------------------------------------------------------------------------
__global__ __launch_bounds__(512)
void rnn_kernel(const int* __restrict__ x,
                const float* __restrict__ Whh,
                const float* __restrict__ P,
                const float* __restrict__ fcw,
                const float* __restrict__ fcb,
                float* __restrict__ out)
{
    __shared__ float hbuf[2][HID];
    __shared__ int   toks[SEQ];
    __shared__ float red[HID];

    const int t  = threadIdx.x;
    const int b  = blockIdx.x;
    const int i  = t >> 2;
    const int kq = t & 3;

    toks[t] = x[b * SEQ + t];          // SEQ == blockDim.x == 512
    if (t < HID) hbuf[0][t] = 0.f;

    // W_hh[i][kq*32 + perm(j)*4 .. +3] into registers (one-time 64KB/block)
    float4 wr[8];
    #pragma unroll
    for (int j = 0; j < 8; ++j) {
        const int pj = (j + 2 * kq) & 7;
        wr[j] = *(const float4*)(Whh + (size_t)i * HID + kq * 32 + pj * 4);
    }
    __syncthreads();

    float xt   = P[(size_t)toks[0] * HID + i];   // prefetched x-projection
    float hmax = -3.0e38f, hsum = 0.f;
    int cur = 0;

    for (int s = 0; s < SEQ; ++s) {
        // prefetch next step's gathered projection (hides L2 latency)
        float xt_next = 0.f;
        if (s + 1 < SEQ) xt_next = P[(size_t)toks[s + 1] * HID + i];

        const float* hb = hbuf[cur];
        float acc = 0.f;
        #pragma unroll
        for (int j = 0; j < 8; ++j) {
            const int pj = (j + 2 * kq) & 7;
            const float4 h4 = *(const float4*)(hb + kq * 32 + pj * 4);
            acc = fmaf(wr[j].x, h4.x, acc);
            acc = fmaf(wr[j].y, h4.y, acc);
            acc = fmaf(wr[j].z, h4.z, acc);
            acc = fmaf(wr[j].w, h4.w, acc);
        }
        // combine the 4 k-quarters (lanes 4i..4i+3, wave-local)
        acc += __shfl_xor(acc, 1);
        acc += __shfl_xor(acc, 2);

        if (kq == 0) {
            const float z = xt + acc;                 // biases already in P
            const float e = __expf(2.f * z);          // tanh via exp
            const float hnew = 1.f - 2.f / (e + 1.f);
            hmax = fmaxf(hmax, hnew);
            hsum += hnew;
            hbuf[cur ^ 1][i] = hnew;
        }
        __syncthreads();   // single barrier/step: double buffer handles WAR
        cur ^= 1;
        xt = xt_next;
    }

    // fused pooling + FC:  out[b] = fcw[0:128]·hmax + fcw[128:256]·(hsum/512) + fcb
    if (kq == 0)
        red[i] = fcw[i] * hmax + fcw[HID + i] * (hsum * (1.f / 512.f));
    __syncthreads();
    if (t < 64) {
        float v = red[t] + red[t + 64];
        #pragma unroll
        for (int m = 32; m >= 1; m >>= 1) v += __shfl_xor(v, m);
        if (t == 0) out[b] = v + fcb[0];
    }
}

// ---------------------------------------------------------------------------
extern "C" void kernel_launch(void* const* d_in, const int* in_sizes, int n_in,
                              void* d_out, int out_size, void* d_ws, size_t ws_size,
                              hipStream_t stream)
{
    const int*   x   = (const int*)  d_in[0];
    const float* emb = (const float*)d_in[1];
    const float* Wih = (const float*)d_in[2];
    const float* Whh = (const float*)d_in[3];
    const float* bih = (const float*)d_in[4];
    const float* bhh = (const float*)d_in[5];
    const float* fcw = (const float*)d_in[6];
    const float* fcb = (const float*)d_in[7];

    float* P = (float*)d_ws;   // needs VOCAB*HID*4 = 25.6 MB of workspace

    proj_kernel<<<VOCAB / VT, 128, 0, stream>>>(emb, Wih, bih, bhh, P);
    rnn_kernel<<<BATCH, 512, 0, stream>>>(x, Whh, P, fcw, fcb, (float*)d_out);
}

// Round 3
// 294.495 us; speedup vs baseline: 1.1862x; 1.1862x over previous
//
#include <hip/hip_runtime.h>

#define HID    128
#define SEQ    512
#define BATCH  256
#define DIM    300
#define VOCAB  50000
#define VT     16      // vocab rows per proj block
#define ETP    20      // padded stride (keeps 8-row float4 groups 16B-aligned)

// ---------------------------------------------------------------------------
// Kernel A: P[v][h] = dot(emb[v,:], W_ih[h,:]) + b_ih[h] + b_hh[h]
// Block 128 thr: hp = t&63 owns h {hp, hp+64}; rg = t>>6 owns 8 of 16 rows.
// W read row-major per-thread float4 (L2-resident, 150KB, heavy reuse);
// emb tile staged transposed in LDS -> wave-uniform broadcast b128 reads.
// Per 4 k: 2 global float4 + 8 broadcast LDS b128 feed 64 FMA -> VALU-bound.
// Workspace use: exactly VOCAB*HID*4 = 25.6 MB (R1-proven safe size).
// ---------------------------------------------------------------------------
__global__ __launch_bounds__(128)
void proj_kernel(const float* __restrict__ emb,
                 const float* __restrict__ Wih,
                 const float* __restrict__ bih,
                 const float* __restrict__ bhh,
                 float* __restrict__ P)
{
    __shared__ float et[DIM][ETP];   // transposed emb tile: et[k][r]
    const int t  = threadIdx.x;
    const int hp = t & 63;
    const int rg = t >> 6;           // 0 or 1
    const int v0 = blockIdx.x * VT;
    const int rg8 = rg * 8;

    #pragma unroll
    for (int r = 0; r < VT; ++r) {
        const float* src = emb + (size_t)(v0 + r) * DIM;
        for (int k = t; k < DIM; k += 128)
            et[k][r] = src[k];
    }
    __syncthreads();

    float a00=0.f,a10=0.f,a20=0.f,a30=0.f,a40=0.f,a50=0.f,a60=0.f,a70=0.f;
    float a01=0.f,a11=0.f,a21=0.f,a31=0.f,a41=0.f,a51=0.f,a61=0.f,a71=0.f;

    const float* w0 = Wih + (size_t)hp * DIM;          // row hp
    const float* w1 = Wih + (size_t)(hp + 64) * DIM;   // row hp+64

    for (int k4 = 0; k4 < DIM / 4; ++k4) {
        const float4 wa4 = *(const float4*)(w0 + k4 * 4);
        const float4 wb4 = *(const float4*)(w1 + k4 * 4);
        #pragma unroll
        for (int jj = 0; jj < 4; ++jj) {
            const float wa = (jj==0)?wa4.x:(jj==1)?wa4.y:(jj==2)?wa4.z:wa4.w;
            const float wb = (jj==0)?wb4.x:(jj==1)?wb4.y:(jj==2)?wb4.z:wb4.w;
            const int k = k4 * 4 + jj;
            const float4 e0 = *(const float4*)(&et[k][rg8]);      // broadcast
            const float4 e1 = *(const float4*)(&et[k][rg8 + 4]);  // broadcast
            a00 = fmaf(wa, e0.x, a00);  a01 = fmaf(wb, e0.x, a01);
            a10 = fmaf(wa, e0.y, a10);  a11 = fmaf(wb, e0.y, a11);
            a20 = fmaf(wa, e0.z, a20);  a21 = fmaf(wb, e0.z, a21);
            a30 = fmaf(wa, e0.w, a30);  a31 = fmaf(wb, e0.w, a31);
            a40 = fmaf(wa, e1.x, a40);  a41 = fmaf(wb, e1.x, a41);
            a50 = fmaf(wa, e1.y, a50);  a51 = fmaf(wb, e1.y, a51);
            a60 = fmaf(wa, e1.z, a60);  a61 = fmaf(wb, e1.z, a61);
            a70 = fmaf(wa, e1.w, a70);  a71 = fmaf(wb, e1.w, a71);
        }
    }

    const float bb0 = bih[hp] + bhh[hp];
    const float bb1 = bih[hp + 64] + bhh[hp + 64];
    float* dst = P + (size_t)(v0 + rg8) * HID;
    dst[0*HID + hp] = a00 + bb0;  dst[0*HID + hp + 64] = a01 + bb1;
    dst[1*HID + hp] = a10 + bb0;  dst[1*HID + hp + 64] = a11 + bb1;
    dst[2*HID + hp] = a20 + bb0;  dst[2*HID + hp + 64] = a21 + bb1;
    dst[3*HID + hp] = a30 + bb0;  dst[3*HID + hp + 64] = a31 + bb1;
    dst[4*HID + hp] = a40 + bb0;  dst[4*HID + hp + 64] = a41 + bb1;
    dst[5*HID + hp] = a50 + bb0;  dst[5*HID + hp + 64] = a51 + bb1;
    dst[6*HID + hp] = a60 + bb0;  dst[6*HID + hp + 64] = a61 + bb1;
    dst[7*HID + hp] = a70 + bb0;  dst[7*HID + hp + 64] = a71 + bb1;
}

// ---------------------------------------------------------------------------
// Kernel B: per-batch sequential RNN. grid=256, block=512.
// Thread t: output i = t>>2, k-quarter kq = t&3 (32 W_hh values in VGPRs).
// DPP quad_perm reduce (pure VALU) instead of ds_swizzle. 4 independent FMA
// chains. P prefetched 4 steps ahead (issued a full STEP before the first
// barrier so the __syncthreads vmcnt drain lands after completion).
// Barrier: plain __syncthreads() — R1-proven race-free under graph replay.
// ---------------------------------------------------------------------------
__device__ __forceinline__ float quad_reduce_add(float v)
{
    // xor1: quad_perm [1,0,3,2] = 0xB1 ; xor2: quad_perm [2,3,0,1] = 0x4E
    int x1 = __builtin_amdgcn_update_dpp(0, __float_as_int(v), 0xB1, 0xF, 0xF, true);
    v += __int_as_float(x1);
    int x2 = __builtin_amdgcn_update_dpp(0, __float_as_int(v), 0x4E, 0xF, 0xF, true);
    v += __int_as_float(x2);
    return v;   // all 4 lanes of the quad hold the sum
}

__global__ __launch_bounds__(512)
void rnn_kernel(const int* __restrict__ x,
                const float* __restrict__ Whh,
                const float* __restrict__ P,
                const float* __restrict__ fcw,
                const float* __restrict__ fcb,
                float* __restrict__ out)
{
    __shared__ float h0b[HID];
    __shared__ float h1b[HID];
    __shared__ int   toff[SEQ];     // token*HID, premultiplied
    __shared__ float red[HID];

    const int t  = threadIdx.x;
    const int b  = blockIdx.x;
    const int i  = t >> 2;
    const int kq = t & 3;

    toff[t] = x[b * SEQ + t] * HID;
    if (t < HID) h0b[t] = 0.f;

    // W_hh[i][kq*32 + rot(j)*4 .. +3]; rotation makes the 4 quad-broadcast
    // ds_read_b128 addresses per j hit disjoint bank quads (0 conflicts).
    float4 wr[8];
    #pragma unroll
    for (int j = 0; j < 8; ++j) {
        const int pj = (j + 2 * kq) & 7;
        wr[j] = *(const float4*)(Whh + (size_t)i * HID + kq * 32 + pj * 4);
    }
    __syncthreads();

    float xt0 = P[toff[0] + i];
    float xt1 = P[toff[1] + i];
    float xt2 = P[toff[2] + i];
    float xt3 = P[toff[3] + i];
    float hmax = -3.0e38f, hsum = 0.f;

#define STEP(HRD, HWR, XT) do {                                               \
        float ac0 = 0.f, ac1 = 0.f, ac2 = 0.f, ac3 = 0.f;                     \
        _Pragma("unroll")                                                     \
        for (int j = 0; j < 8; ++j) {                                         \
            const int pj = (j + 2 * kq) & 7;                                  \
            const float4 h4 = *(const float4*)(HRD + kq * 32 + pj * 4);       \
            float* accp = (j & 3) == 0 ? &ac0 : (j & 3) == 1 ? &ac1           \
                         : (j & 3) == 2 ? &ac2 : &ac3;                        \
            *accp = fmaf(wr[j].x, h4.x, *accp);                               \
            *accp = fmaf(wr[j].y, h4.y, *accp);                               \
            *accp = fmaf(wr[j].z, h4.z, *accp);                               \
            *accp = fmaf(wr[j].w, h4.w, *accp);                               \
        }                                                                     \
        float acc = (ac0 + ac1) + (ac2 + ac3);                                \
        acc = quad_reduce_add(acc);                                           \
        const float z = (XT) + acc;                                           \
        const float e = __builtin_amdgcn_exp2f(z * 2.8853900817779268f);      \
        const float hnew = fmaf(-2.f, __builtin_amdgcn_rcpf(e + 1.f), 1.f);   \
        hmax = fmaxf(hmax, hnew);                                             \
        hsum += hnew;                                                         \
        if (kq == 0) (HWR)[i] = hnew;                                         \
        __syncthreads();                                                      \
    } while (0)

    for (int s = 0; s < SEQ - 4; s += 4) {
        float n0 = P[toff[s + 4] + i];
        float n1 = P[toff[s + 5] + i];
        float n2 = P[toff[s + 6] + i];
        float n3 = P[toff[s + 7] + i];
        STEP(h0b, h1b, xt0);
        STEP(h1b, h0b, xt1);
        STEP(h0b, h1b, xt2);
        STEP(h1b, h0b, xt3);
        xt0 = n0; xt1 = n1; xt2 = n2; xt3 = n3;
    }
    STEP(h0b, h1b, xt0);
    STEP(h1b, h0b, xt1);
    STEP(h0b, h1b, xt2);
    STEP(h1b, h0b, xt3);
#undef STEP

    // fused pooling + FC: out[b] = fcw[0:128]·hmax + fcw[128:256]·(hsum/512) + fcb
    if (kq == 0)
        red[i] = fcw[i] * hmax + fcw[HID + i] * (hsum * (1.f / 512.f));
    __syncthreads();
    if (t < 64) {
        float v = red[t] + red[t + 64];
        #pragma unroll
        for (int m = 32; m >= 1; m >>= 1) v += __shfl_xor(v, m);
        if (t == 0) out[b] = v + fcb[0];
    }
}

// ---------------------------------------------------------------------------
extern "C" void kernel_launch(void* const* d_in, const int* in_sizes, int n_in,
                              void* d_out, int out_size, void* d_ws, size_t ws_size,
                              hipStream_t stream)
{
    const int*   x   = (const int*)  d_in[0];
    const float* emb = (const float*)d_in[1];
    const float* Wih = (const float*)d_in[2];
    const float* Whh = (const float*)d_in[3];
    const float* bih = (const float*)d_in[4];
    const float* bhh = (const float*)d_in[5];
    const float* fcw = (const float*)d_in[6];
    const float* fcb = (const float*)d_in[7];

    float* P = (float*)d_ws;   // exactly VOCAB*HID*4 = 25.6 MB of workspace

    proj_kernel<<<VOCAB / VT, 128, 0, stream>>>(emb, Wih, bih, bhh, P);
    rnn_kernel<<<BATCH, 512, 0, stream>>>(x, Whh, P, fcw, fcb, (float*)d_out);
}

// Round 4
// 284.830 us; speedup vs baseline: 1.2265x; 1.0339x over previous
//
#include <hip/hip_runtime.h>

#define HID    128
#define SEQ    512
#define BATCH  256
#define DIM    300
#define VOCAB  50000
#define VT     16      // vocab rows per proj block
#define ETP    20      // padded stride (keeps 8-row float4 groups 16B-aligned)
#define WT_FLOATS 40960  // 160 KB slot for packed-transposed W_ih (needs 38400)

// ---------------------------------------------------------------------------
// Kernel 0: pack-transpose W_ih [128][300] -> Wt[k4][h][4] so proj's W reads
// are lane-consecutive float4 (one fully-coalesced 1KB transaction per inst).
// ---------------------------------------------------------------------------
__global__ __launch_bounds__(256)
void wtrans_kernel(const float* __restrict__ Wih, float* __restrict__ Wt)
{
    int idx = blockIdx.x * 256 + threadIdx.x;
    if (idx < HID * DIM) {
        int h = idx / DIM;
        int k = idx - h * DIM;
        Wt[(k >> 2) * (HID * 4) + h * 4 + (k & 3)] = Wih[idx];
    }
}

// ---------------------------------------------------------------------------
// Kernel A (fast): P[v][h] = dot(emb[v,:], W_ih[h,:]) + b_ih[h] + b_hh[h]
// Block 128 thr: hp = t&63 owns h {hp, hp+64}; rg = t>>6 owns 8 of 16 rows.
// Per k4: 2 coalesced global float4 (Wt) + 8 broadcast LDS b128 + 64 FMA.
// ---------------------------------------------------------------------------
__global__ __launch_bounds__(128)
void proj_fast(const float* __restrict__ emb,
               const float* __restrict__ Wt,
               const float* __restrict__ bih,
               const float* __restrict__ bhh,
               float* __restrict__ P)
{
    __shared__ float et[DIM][ETP];   // transposed emb tile: et[k][r]
    const int t  = threadIdx.x;
    const int hp = t & 63;
    const int rg8 = (t >> 6) * 8;
    const int v0 = blockIdx.x * VT;

    #pragma unroll
    for (int r = 0; r < VT; ++r) {
        const float* src = emb + (size_t)(v0 + r) * DIM;
        for (int k = t; k < DIM; k += 128)
            et[k][r] = src[k];
    }
    __syncthreads();

    float a00=0.f,a10=0.f,a20=0.f,a30=0.f,a40=0.f,a50=0.f,a60=0.f,a70=0.f;
    float a01=0.f,a11=0.f,a21=0.f,a31=0.f,a41=0.f,a51=0.f,a61=0.f,a71=0.f;

    const float* wp0 = Wt + hp * 4;          // packed: [k4][h][4]
    const float* wp1 = Wt + (hp + 64) * 4;

    for (int k4 = 0; k4 < DIM / 4; ++k4) {
        const float4 wa4 = *(const float4*)(wp0 + k4 * (HID * 4));
        const float4 wb4 = *(const float4*)(wp1 + k4 * (HID * 4));
        #pragma unroll
        for (int jj = 0; jj < 4; ++jj) {
            const float wa = (jj==0)?wa4.x:(jj==1)?wa4.y:(jj==2)?wa4.z:wa4.w;
            const float wb = (jj==0)?wb4.x:(jj==1)?wb4.y:(jj==2)?wb4.z:wb4.w;
            const int k = k4 * 4 + jj;
            const float4 e0 = *(const float4*)(&et[k][rg8]);      // broadcast
            const float4 e1 = *(const float4*)(&et[k][rg8 + 4]);  // broadcast
            a00 = fmaf(wa, e0.x, a00);  a01 = fmaf(wb, e0.x, a01);
            a10 = fmaf(wa, e0.y, a10);  a11 = fmaf(wb, e0.y, a11);
            a20 = fmaf(wa, e0.z, a20);  a21 = fmaf(wb, e0.z, a21);
            a30 = fmaf(wa, e0.w, a30);  a31 = fmaf(wb, e0.w, a31);
            a40 = fmaf(wa, e1.x, a40);  a41 = fmaf(wb, e1.x, a41);
            a50 = fmaf(wa, e1.y, a50);  a51 = fmaf(wb, e1.y, a51);
            a60 = fmaf(wa, e1.z, a60);  a61 = fmaf(wb, e1.z, a61);
            a70 = fmaf(wa, e1.w, a70);  a71 = fmaf(wb, e1.w, a71);
        }
    }

    const float bb0 = bih[hp] + bhh[hp];
    const float bb1 = bih[hp + 64] + bhh[hp + 64];
    float* dst = P + (size_t)(v0 + rg8) * HID;
    dst[0*HID + hp] = a00 + bb0;  dst[0*HID + hp + 64] = a01 + bb1;
    dst[1*HID + hp] = a10 + bb0;  dst[1*HID + hp + 64] = a11 + bb1;
    dst[2*HID + hp] = a20 + bb0;  dst[2*HID + hp + 64] = a21 + bb1;
    dst[3*HID + hp] = a30 + bb0;  dst[3*HID + hp + 64] = a31 + bb1;
    dst[4*HID + hp] = a40 + bb0;  dst[4*HID + hp + 64] = a41 + bb1;
    dst[5*HID + hp] = a50 + bb0;  dst[5*HID + hp + 64] = a51 + bb1;
    dst[6*HID + hp] = a60 + bb0;  dst[6*HID + hp + 64] = a61 + bb1;
    dst[7*HID + hp] = a70 + bb0;  dst[7*HID + hp + 64] = a71 + bb1;
}

// ---------------------------------------------------------------------------
// Kernel A (fallback, R3-proven): used only if ws_size can't fit Wt + P.
// ---------------------------------------------------------------------------
__global__ __launch_bounds__(128)
void proj_fallback(const float* __restrict__ emb,
                   const float* __restrict__ Wih,
                   const float* __restrict__ bih,
                   const float* __restrict__ bhh,
                   float* __restrict__ P)
{
    __shared__ float et[DIM][ETP];
    const int t  = threadIdx.x;
    const int hp = t & 63;
    const int rg8 = (t >> 6) * 8;
    const int v0 = blockIdx.x * VT;

    #pragma unroll
    for (int r = 0; r < VT; ++r) {
        const float* src = emb + (size_t)(v0 + r) * DIM;
        for (int k = t; k < DIM; k += 128)
            et[k][r] = src[k];
    }
    __syncthreads();

    float a00=0.f,a10=0.f,a20=0.f,a30=0.f,a40=0.f,a50=0.f,a60=0.f,a70=0.f;
    float a01=0.f,a11=0.f,a21=0.f,a31=0.f,a41=0.f,a51=0.f,a61=0.f,a71=0.f;

    const float* w0 = Wih + (size_t)hp * DIM;
    const float* w1 = Wih + (size_t)(hp + 64) * DIM;

    for (int k4 = 0; k4 < DIM / 4; ++k4) {
        const float4 wa4 = *(const float4*)(w0 + k4 * 4);
        const float4 wb4 = *(const float4*)(w1 + k4 * 4);
        #pragma unroll
        for (int jj = 0; jj < 4; ++jj) {
            const float wa = (jj==0)?wa4.x:(jj==1)?wa4.y:(jj==2)?wa4.z:wa4.w;
            const float wb = (jj==0)?wb4.x:(jj==1)?wb4.y:(jj==2)?wb4.z:wb4.w;
            const int k = k4 * 4 + jj;
            const float4 e0 = *(const float4*)(&et[k][rg8]);
            const float4 e1 = *(const float4*)(&et[k][rg8 + 4]);
            a00 = fmaf(wa, e0.x, a00);  a01 = fmaf(wb, e0.x, a01);
            a10 = fmaf(wa, e0.y, a10);  a11 = fmaf(wb, e0.y, a11);
            a20 = fmaf(wa, e0.z, a20);  a21 = fmaf(wb, e0.z, a21);
            a30 = fmaf(wa, e0.w, a30);  a31 = fmaf(wb, e0.w, a31);
            a40 = fmaf(wa, e1.x, a40);  a41 = fmaf(wb, e1.x, a41);
            a50 = fmaf(wa, e1.y, a50);  a51 = fmaf(wb, e1.y, a51);
            a60 = fmaf(wa, e1.z, a60);  a61 = fmaf(wb, e1.z, a61);
            a70 = fmaf(wa, e1.w, a70);  a71 = fmaf(wb, e1.w, a71);
        }
    }

    const float bb0 = bih[hp] + bhh[hp];
    const float bb1 = bih[hp + 64] + bhh[hp + 64];
    float* dst = P + (size_t)(v0 + rg8) * HID;
    dst[0*HID + hp] = a00 + bb0;  dst[0*HID + hp + 64] = a01 + bb1;
    dst[1*HID + hp] = a10 + bb0;  dst[1*HID + hp + 64] = a11 + bb1;
    dst[2*HID + hp] = a20 + bb0;  dst[2*HID + hp + 64] = a21 + bb1;
    dst[3*HID + hp] = a30 + bb0;  dst[3*HID + hp + 64] = a31 + bb1;
    dst[4*HID + hp] = a40 + bb0;  dst[4*HID + hp + 64] = a41 + bb1;
    dst[5*HID + hp] = a50 + bb0;  dst[5*HID + hp + 64] = a51 + bb1;
    dst[6*HID + hp] = a60 + bb0;  dst[6*HID + hp + 64] = a61 + bb1;
    dst[7*HID + hp] = a70 + bb0;  dst[7*HID + hp + 64] = a71 + bb1;
}

// ---------------------------------------------------------------------------
// Kernel B: per-batch sequential RNN — BYTE-IDENTICAL to R3 (189 µs measured).
// ---------------------------------------------------------------------------
__device__ __forceinline__ float quad_reduce_add(float v)
{
    int x1 = __builtin_amdgcn_update_dpp(0, __float_as_int(v), 0xB1, 0xF, 0xF, true);
    v += __int_as_float(x1);
    int x2 = __builtin_amdgcn_update_dpp(0, __float_as_int(v), 0x4E, 0xF, 0xF, true);
    v += __int_as_float(x2);
    return v;
}

__global__ __launch_bounds__(512)
void rnn_kernel(const int* __restrict__ x,
                const float* __restrict__ Whh,
                const float* __restrict__ P,
                const float* __restrict__ fcw,
                const float* __restrict__ fcb,
                float* __restrict__ out)
{
    __shared__ float h0b[HID];
    __shared__ float h1b[HID];
    __shared__ int   toff[SEQ];
    __shared__ float red[HID];

    const int t  = threadIdx.x;
    const int b  = blockIdx.x;
    const int i  = t >> 2;
    const int kq = t & 3;

    toff[t] = x[b * SEQ + t] * HID;
    if (t < HID) h0b[t] = 0.f;

    float4 wr[8];
    #pragma unroll
    for (int j = 0; j < 8; ++j) {
        const int pj = (j + 2 * kq) & 7;
        wr[j] = *(const float4*)(Whh + (size_t)i * HID + kq * 32 + pj * 4);
    }
    __syncthreads();

    float xt0 = P[toff[0] + i];
    float xt1 = P[toff[1] + i];
    float xt2 = P[toff[2] + i];
    float xt3 = P[toff[3] + i];
    float hmax = -3.0e38f, hsum = 0.f;

#define STEP(HRD, HWR, XT) do {                                               \
        float ac0 = 0.f, ac1 = 0.f, ac2 = 0.f, ac3 = 0.f;                     \
        _Pragma("unroll")                                                     \
        for (int j = 0; j < 8; ++j) {                                         \
            const int pj = (j + 2 * kq) & 7;                                  \
            const float4 h4 = *(const float4*)(HRD + kq * 32 + pj * 4);       \
            float* accp = (j & 3) == 0 ? &ac0 : (j & 3) == 1 ? &ac1           \
                         : (j & 3) == 2 ? &ac2 : &ac3;                        \
            *accp = fmaf(wr[j].x, h4.x, *accp);                               \
            *accp = fmaf(wr[j].y, h4.y, *accp);                               \
            *accp = fmaf(wr[j].z, h4.z, *accp);                               \
            *accp = fmaf(wr[j].w, h4.w, *accp);                               \
        }                                                                     \
        float acc = (ac0 + ac1) + (ac2 + ac3);                                \
        acc = quad_reduce_add(acc);                                           \
        const float z = (XT) + acc;                                           \
        const float e = __builtin_amdgcn_exp2f(z * 2.8853900817779268f);      \
        const float hnew = fmaf(-2.f, __builtin_amdgcn_rcpf(e + 1.f), 1.f);   \
        hmax = fmaxf(hmax, hnew);                                             \
        hsum += hnew;                                                         \
        if (kq == 0) (HWR)[i] = hnew;                                         \
        __syncthreads();                                                      \
    } while (0)

    for (int s = 0; s < SEQ - 4; s += 4) {
        float n0 = P[toff[s + 4] + i];
        float n1 = P[toff[s + 5] + i];
        float n2 = P[toff[s + 6] + i];
        float n3 = P[toff[s + 7] + i];
        STEP(h0b, h1b, xt0);
        STEP(h1b, h0b, xt1);
        STEP(h0b, h1b, xt2);
        STEP(h1b, h0b, xt3);
        xt0 = n0; xt1 = n1; xt2 = n2; xt3 = n3;
    }
    STEP(h0b, h1b, xt0);
    STEP(h1b, h0b, xt1);
    STEP(h0b, h1b, xt2);
    STEP(h1b, h0b, xt3);
#undef STEP

    if (kq == 0)
        red[i] = fcw[i] * hmax + fcw[HID + i] * (hsum * (1.f / 512.f));
    __syncthreads();
    if (t < 64) {
        float v = red[t] + red[t + 64];
        #pragma unroll
        for (int m = 32; m >= 1; m >>= 1) v += __shfl_xor(v, m);
        if (t == 0) out[b] = v + fcb[0];
    }
}

// ---------------------------------------------------------------------------
extern "C" void kernel_launch(void* const* d_in, const int* in_sizes, int n_in,
                              void* d_out, int out_size, void* d_ws, size_t ws_size,
                              hipStream_t stream)
{
    const int*   x   = (const int*)  d_in[0];
    const float* emb = (const float*)d_in[1];
    const float* Wih = (const float*)d_in[2];
    const float* Whh = (const float*)d_in[3];
    const float* bih = (const float*)d_in[4];
    const float* bhh = (const float*)d_in[5];
    const float* fcw = (const float*)d_in[6];
    const float* fcb = (const float*)d_in[7];

    float* base = (float*)d_ws;
    const size_t need = (WT_FLOATS + (size_t)VOCAB * HID) * sizeof(float);
    float* P;

    if (ws_size >= need) {
        float* Wt = base;                 // 160 KB slot, fully inside d_ws
        P = base + WT_FLOATS;             // 25.6 MB
        wtrans_kernel<<<(HID * DIM + 255) / 256, 256, 0, stream>>>(Wih, Wt);
        proj_fast<<<VOCAB / VT, 128, 0, stream>>>(emb, Wt, bih, bhh, P);
    } else {
        P = base;                         // R3 layout, R3 kernel
        proj_fallback<<<VOCAB / VT, 128, 0, stream>>>(emb, Wih, bih, bhh, P);
    }

    rnn_kernel<<<BATCH, 512, 0, stream>>>(x, Whh, P, fcw, fcb, (float*)d_out);
}